// Round 8
// baseline (444.610 us; speedup 1.0000x reference)
//
#include <hip/hip_runtime.h>
#include <hip/hip_cooperative_groups.h>

// ErosionLayer: B=16, W=512, ITERS=10, fp32. PASSING numeric recipe (r5/r6,
// absmax 0.02734375): XLA-style greedy FMA via explicit fmaf() at exact sites,
// contract(off) elsewhere, correctly-rounded fp32 div/sqrt. DO NOT change op
// order or fusion sites.
//
// r8: cooperative megakernel, 512 blocks x 256 thr x 32 cells/thr
// (launch_bounds(256,2): VGPR<=256, needs only 2 blocks/CU — 2x slack vs the
// r7 1024-block config that silently failed to launch). sed/wat/vel live in
// registers across all 10 steps; terrain double-buffered (T0=d_out, T1=ws)
// with grid.sync() + device fences between steps (cross-XCD halo visibility).
// Runtime routing: occupancy query decides coop vs the proven r6 multi-kernel
// fallback (both deterministic, capture-safe).
#pragma clang fp contract(off)

namespace cg = cooperative_groups;

constexpr int WW    = 512;
constexpr int NPIX  = WW * WW;       // 2^18
constexpr int NTOT  = 16 * NPIX;     // 4194304
constexpr int NTHR  = 256;
constexpr int CELLS = 32;
constexpr int NBLK  = NTOT / (NTHR * CELLS);   // 512

// ---------------------------------------------------------------- shared math
// The exact r5/r6 per-cell step. Inputs: t_c (center terrain), tb (terrain
// image base), state s,w0,v; outputs via refs. Identical op order/fusions.
__device__ __forceinline__ void cell_step(
    const float* __restrict__ tb, int rem, int r, int c, float t_c,
    float rain_v, float gno_v,
    float rr, float evapr, float minhd, float heps, float gravr, float sccr,
    float diss, float depo,
    float& s_io, float& w_io, float& v_io, float& t_out, bool fin)
{
    #pragma clang fp contract(off)
    const float CELLW = 0.390625f;            // 200/512, exact

    // water = water + relu(rain_rate)*rain  -> fma
    float w = fmaf(rr, rain_v, w_io);

    // --- simple_gradient; boundary t*1.1 - t -> fma(t, 1.1, -t) ---
    float dx, dy;
    if      (r == 0)      dx = 0.5f * fmaf(t_c, 1.1f, -t_c);
    else if (r == WW - 1) dx = 0.5f * fmaf(t_c, 0.9f, -t_c);
    else                  dx = 0.5f * (tb[rem + WW] - tb[rem - WW]);
    if      (c == 0)      dy = 0.5f * fmaf(t_c, 1.1f, -t_c);
    else if (c == WW - 1) dy = 0.5f * fmaf(t_c, 0.9f, -t_c);
    else                  dy = 0.5f * (tb[rem + 1] - tb[rem - 1]);

    float mag = sqrtf(fmaf(dx, dx, dy * dy) + 1e-11f);

    float rX  = gno_v;
    float rY  = sqrtf(fmaf(-rX, rX, 1.0f));   // 1 - rX*rX -> fnma

    float factor = fmaxf(1e-10f - mag, 0.0f); // always 0; kept for fidelity
    float den = mag + factor;
    float fdx = fmaf(factor, rX, dx) / den;
    float fdy = fmaf(factor, rY, dy) / den;

    // --- bilinear_sample(terrain, -gradient) ---
    float fx  = (float)c + (-fdx);
    float fy  = (float)r + (-fdy);
    float x0f = floorf(fx), y0f = floorf(fy);
    float wx1 = fx - x0f;
    float wy1 = fy - y0f;
    int x0 = (int)x0f, y0 = (int)y0f;
    int x1 = x0 + 1,   y1 = y0 + 1;

    bool vx0 = (x0 >= 0) & (x0 < WW);
    bool vx1 = (x1 >= 0) & (x1 < WW);
    bool vy0 = (y0 >= 0) & (y0 < WW);
    bool vy1 = (y1 >= 0) & (y1 < WW);
    int x0c = min(max(x0, 0), WW - 1), x1c = min(max(x1, 0), WW - 1);
    int y0c = min(max(y0, 0), WW - 1), y1c = min(max(y1, 0), WW - 1);

    float g00 = (vx0 && vy0) ? (tb[y0c * WW + x0c] - 1.0f) : 0.0f;
    float g10 = (vx1 && vy0) ? (tb[y0c * WW + x1c] - 1.0f) : 0.0f;
    float g01 = (vx0 && vy1) ? (tb[y1c * WW + x0c] - 1.0f) : 0.0f;
    float g11 = (vx1 && vy1) ? (tb[y1c * WW + x1c] - 1.0f) : 0.0f;

    float wx0 = 1.0f - wx1;
    float wy0 = 1.0f - wy1;
    float rowA = fmaf(wx0, g00, wx1 * g10);
    float rowB = fmaf(wx0, g01, wx1 * g11);
    float bil  = fmaf(wy0, rowA, wy1 * rowB);
    float neighbor = bil + 1.0f;

    float hd = t_c - neighbor;

    // --- state update ---
    float v = v_io;
    float s = s_io;

    float hds  = ((hd - heps) > 0.0f) ? 1.0f : 0.0f;     // sign(relu(hd-eps))
    float nhd  = hds * fmaxf(hd, minhd);
    float q1 = nhd / CELLW;
    float q2 = q1 * v;
    float q3 = q2 * w;
    float sdiff = fmaf(-q3, sccr, s);                    // s - sed_cap
    float ftb   = (hd < 0.0f) ? 1.0f : 0.0f;             // relu(sign(-hd))
    float first = fminf(fmaxf(-hd, 0.0f), s);
    float ra = fmaxf(sdiff * depo, 0.0f);
    float rb = fmaxf((-sdiff) * diss, 0.0f);
    float deparg = fmaf(1.0f - ftb, ra - rb, first);
    float dep    = fmaxf(-fmaxf(hd, 0.0f), deparg);

    float s_new = s - dep;
    float t_new = t_c + dep;

    // --- displace: (sel(t1) + fma(rm,a)) + sel(t3) ---
    float rn = fmaxf(-fdy, 0.0f);
    float rm = fmaxf(1.0f - fabsf(fdy), 0.0f);
    float rp = fmaxf(fdy, 0.0f);

    float s1 = (c == WW - 1) ? 0.0f : rn * s_new;
    float s3 = (c == 0)      ? 0.0f : rp * s_new;
    s_io = fmaf(rm, s_new, s1) + s3;

    float w1 = (c == WW - 1) ? 0.0f : rn * w;
    float w3 = (c == 0)      ? 0.0f : rp * w;
    float wd = fmaf(rm, w, w1) + w3;
    w_io = wd * (1.0f - evapr);

    v_io = (gravr * hd) / CELLW;

    if (fin) {
        float aa = fmaf(-t_new, 2.0f, 1.0f);             // 1 - t*2 -> fnma
        float bq = 1.0f + aa;
        t_out = fmaxf(bq, 0.0f) - 1.0f;
    } else {
        t_out = t_new;
    }
}

// ---------------------------------------------------------------- coop path
struct Args {
    const float* in_terr;
    float*       T0;      // d_out: even-step source, final output
    float*       T1;      // ws
    const float* rain;    // (10, W, W)
    const float* gno;     // (10, W, W)
    const float* p_rr; const float* p_evap; const float* p_minhd;
    const float* p_heps; const float* p_grav; const float* p_scc;
    const float* p_diss; const float* p_depo;
};

__global__ __launch_bounds__(256, 2) void erosion_mega(Args a)
{
    #pragma clang fp contract(off)
    cg::grid_group grid = cg::this_grid();

    const int base = blockIdx.x * (NTHR * CELLS) + threadIdx.x;

    float rr    = fmaxf(a.p_rr[0], 0.0f);
    float evapr = fmaxf(a.p_evap[0], 0.0f);
    float minhd = a.p_minhd[0];
    float heps  = a.p_heps[0];
    float gravr = fmaxf(a.p_grav[0], 0.0f);
    float sccr  = fmaxf(a.p_scc[0], 0.0f);
    float diss  = a.p_diss[0];
    float depo  = a.p_depo[0];

    float sA[CELLS], wA[CELLS], vA[CELLS];
    #pragma unroll
    for (int k = 0; k < CELLS; ++k) {
        int idx = base + k * NTHR;
        a.T0[idx] = (1.0f - a.in_terr[idx]) / 2.0f;
        sA[k] = 0.0f; wA[k] = 0.0f; vA[k] = 0.0f;
    }
    __threadfence();
    grid.sync();
    __threadfence();

    #pragma unroll 1
    for (int it = 0; it < 10; ++it) {
        const float* tin  = (it & 1) ? a.T1 : a.T0;
        float*       tout = (it & 1) ? a.T0 : a.T1;
        const float* rain = a.rain + it * NPIX;
        const float* gno  = a.gno  + it * NPIX;
        const bool   fin  = (it == 9);

        #pragma unroll
        for (int k = 0; k < CELLS; ++k) {
            int idx = base + k * NTHR;
            int rem = idx & (NPIX - 1);
            int r   = rem >> 9;
            int c   = rem & (WW - 1);
            const float* tb = tin + (idx - rem);
            float t_res;
            cell_step(tb, rem, r, c, tb[rem], rain[rem], gno[rem],
                      rr, evapr, minhd, heps, gravr, sccr, diss, depo,
                      sA[k], wA[k], vA[k], t_res, fin);
            tout[idx] = t_res;
        }

        if (it != 9) {
            __threadfence();
            grid.sync();
            __threadfence();
        }
    }
}

// ---------------------------------------------------------------- fallback (r6)
__global__ __launch_bounds__(256) void erosion_init(
    const float* __restrict__ in, float* __restrict__ terr,
    float* __restrict__ sed, float* __restrict__ wat, float* __restrict__ vel)
{
    #pragma clang fp contract(off)
    int idx = blockIdx.x * 256 + threadIdx.x;
    terr[idx] = (1.0f - in[idx]) / 2.0f;
    sed[idx] = 0.0f;
    wat[idx] = 0.0f;
    vel[idx] = 0.0f;
}

__global__ __launch_bounds__(256) void erosion_step(
    const float* __restrict__ terr_in, float* __restrict__ terr_out,
    float* __restrict__ sed, float* __restrict__ wat, float* __restrict__ vel,
    const float* __restrict__ rain, const float* __restrict__ gnoise,
    const float* __restrict__ s_rain_rate, const float* __restrict__ s_evap,
    const float* __restrict__ s_minhd, const float* __restrict__ s_heps,
    const float* __restrict__ s_grav, const float* __restrict__ s_scc,
    const float* __restrict__ s_diss, const float* __restrict__ s_depo,
    int final_flag)
{
    #pragma clang fp contract(off)
    int idx = blockIdx.x * 256 + threadIdx.x;
    int rem = idx & (NPIX - 1);
    int r   = rem >> 9;
    int c   = rem & (WW - 1);
    const float* tb = terr_in + (long)(idx - rem);

    float rr    = fmaxf(s_rain_rate[0], 0.0f);
    float evapr = fmaxf(s_evap[0], 0.0f);
    float minhd = s_minhd[0];
    float heps  = s_heps[0];
    float gravr = fmaxf(s_grav[0], 0.0f);
    float sccr  = fmaxf(s_scc[0], 0.0f);
    float diss  = s_diss[0];
    float depo  = s_depo[0];

    float s = sed[idx], w0 = wat[idx], v = vel[idx];
    float t_res;
    cell_step(tb, rem, r, c, tb[rem], rain[rem], gnoise[rem],
              rr, evapr, minhd, heps, gravr, sccr, diss, depo,
              s, w0, v, t_res, final_flag != 0);
    sed[idx] = s; wat[idx] = w0; vel[idx] = v;
    terr_out[idx] = t_res;
}

// ---------------------------------------------------------------- launch
extern "C" void kernel_launch(void* const* d_in, const int* in_sizes, int n_in,
                              void* d_out, int out_size, void* d_ws, size_t ws_size,
                              hipStream_t stream) {
    Args a;
    a.in_terr = (const float*)d_in[0];
    a.rain    = (const float*)d_in[1];
    a.gno     = (const float*)d_in[2];
    a.p_rr    = (const float*)d_in[3];
    a.p_evap  = (const float*)d_in[4];
    a.p_minhd = (const float*)d_in[5];
    a.p_heps  = (const float*)d_in[6];
    a.p_grav  = (const float*)d_in[7];
    a.p_scc   = (const float*)d_in[8];
    a.p_diss  = (const float*)d_in[9];
    a.p_depo  = (const float*)d_in[10];
    a.T0      = (float*)d_out;
    a.T1      = (float*)d_ws;

    // Host-side routing (capture-legal, deterministic): coop only if the whole
    // grid is provably co-resident.
    bool coop_ok = false;
    int dev = 0;
    (void)hipGetDevice(&dev);
    int numCU = 0;
    if (hipDeviceGetAttribute(&numCU, hipDeviceAttributeMultiprocessorCount, dev) == hipSuccess) {
        int perCU = 0;
        if (hipOccupancyMaxActiveBlocksPerMultiprocessor(&perCU, (const void*)erosion_mega,
                                                         NTHR, 0) == hipSuccess) {
            coop_ok = ((long)perCU * numCU >= NBLK);
        }
    }

    if (coop_ok) {
        void* kargs[] = { &a };
        if (hipLaunchCooperativeKernel((void*)erosion_mega, dim3(NBLK), dim3(NTHR),
                                       kargs, 0, stream) == hipSuccess)
            return;
    }

    // Fallback: proven r6 multi-kernel sequence (442 us, absmax 0.0273).
    float* T0  = (float*)d_out;
    float* ws  = (float*)d_ws;
    float* T1  = ws;
    float* sed = ws + (size_t)NTOT;
    float* wat = ws + (size_t)2 * NTOT;
    float* vel = ws + (size_t)3 * NTOT;

    dim3 grid(NTOT / 256), block(256);
    erosion_init<<<grid, block, 0, stream>>>(a.in_terr, T0, sed, wat, vel);
    for (int it = 0; it < 10; ++it) {
        const float* tin  = (it & 1) ? T1 : T0;
        float*       tout = (it & 1) ? T0 : T1;
        erosion_step<<<grid, block, 0, stream>>>(
            tin, tout, sed, wat, vel,
            a.rain + (size_t)it * NPIX, a.gno + (size_t)it * NPIX,
            a.p_rr, a.p_evap, a.p_minhd, a.p_heps, a.p_grav, a.p_scc,
            a.p_diss, a.p_depo, (it == 9) ? 1 : 0);
    }
}

// Round 9
// 436.157 us; speedup vs baseline: 1.0194x; 1.0194x over previous
//
#include <hip/hip_runtime.h>
#include <hip/hip_cooperative_groups.h>

// ErosionLayer: B=16, W=512, ITERS=10, fp32. PASSING numeric recipe (r5/r6/r8,
// absmax 0.02734375): XLA-style greedy FMA via explicit fmaf() at exact sites,
// contract(off) elsewhere, correctly-rounded fp32 div/sqrt. DO NOT change op
// order or fusion sites (cell_step is frozen).
//
// r9: mega-kernel geometry change only. r8 (512 blk x 256 thr, fences) was
// sync/latency-bound: 24% occupancy, per-thread __threadfence() x2/step
// (device-scope L2 wb/inv from every thread), 1.2 TB/s effective. r9:
// 256 blocks x 1024 thr x 16 cells (50% occupancy, 1 block/CU, 256 barrier
// arrivals), explicit fences dropped — cg::grid.sync() provides grid-wide
// acq/rel ordering internally. Routing: occupancy query -> coop; else r6
// fallback sequence (proven 442 us).
#pragma clang fp contract(off)

namespace cg = cooperative_groups;

constexpr int WW    = 512;
constexpr int NPIX  = WW * WW;       // 2^18
constexpr int NTOT  = 16 * NPIX;     // 4194304
constexpr int MTHR  = 1024;          // mega block size
constexpr int CELLS = 16;
constexpr int NBLK  = NTOT / (MTHR * CELLS);   // 256

// ---------------------------------------------------------------- shared math
// FROZEN r5/r6 per-cell step: identical op order/fusions.
__device__ __forceinline__ void cell_step(
    const float* __restrict__ tb, int rem, int r, int c, float t_c,
    float rain_v, float gno_v,
    float rr, float evapr, float minhd, float heps, float gravr, float sccr,
    float diss, float depo,
    float& s_io, float& w_io, float& v_io, float& t_out, bool fin)
{
    #pragma clang fp contract(off)
    const float CELLW = 0.390625f;            // 200/512, exact

    float w = fmaf(rr, rain_v, w_io);

    float dx, dy;
    if      (r == 0)      dx = 0.5f * fmaf(t_c, 1.1f, -t_c);
    else if (r == WW - 1) dx = 0.5f * fmaf(t_c, 0.9f, -t_c);
    else                  dx = 0.5f * (tb[rem + WW] - tb[rem - WW]);
    if      (c == 0)      dy = 0.5f * fmaf(t_c, 1.1f, -t_c);
    else if (c == WW - 1) dy = 0.5f * fmaf(t_c, 0.9f, -t_c);
    else                  dy = 0.5f * (tb[rem + 1] - tb[rem - 1]);

    float mag = sqrtf(fmaf(dx, dx, dy * dy) + 1e-11f);

    float rX  = gno_v;
    float rY  = sqrtf(fmaf(-rX, rX, 1.0f));   // 1 - rX*rX -> fnma

    float factor = fmaxf(1e-10f - mag, 0.0f); // always 0; kept for fidelity
    float den = mag + factor;
    float fdx = fmaf(factor, rX, dx) / den;
    float fdy = fmaf(factor, rY, dy) / den;

    float fx  = (float)c + (-fdx);
    float fy  = (float)r + (-fdy);
    float x0f = floorf(fx), y0f = floorf(fy);
    float wx1 = fx - x0f;
    float wy1 = fy - y0f;
    int x0 = (int)x0f, y0 = (int)y0f;
    int x1 = x0 + 1,   y1 = y0 + 1;

    bool vx0 = (x0 >= 0) & (x0 < WW);
    bool vx1 = (x1 >= 0) & (x1 < WW);
    bool vy0 = (y0 >= 0) & (y0 < WW);
    bool vy1 = (y1 >= 0) & (y1 < WW);
    int x0c = min(max(x0, 0), WW - 1), x1c = min(max(x1, 0), WW - 1);
    int y0c = min(max(y0, 0), WW - 1), y1c = min(max(y1, 0), WW - 1);

    float g00 = (vx0 && vy0) ? (tb[y0c * WW + x0c] - 1.0f) : 0.0f;
    float g10 = (vx1 && vy0) ? (tb[y0c * WW + x1c] - 1.0f) : 0.0f;
    float g01 = (vx0 && vy1) ? (tb[y1c * WW + x0c] - 1.0f) : 0.0f;
    float g11 = (vx1 && vy1) ? (tb[y1c * WW + x1c] - 1.0f) : 0.0f;

    float wx0 = 1.0f - wx1;
    float wy0 = 1.0f - wy1;
    float rowA = fmaf(wx0, g00, wx1 * g10);
    float rowB = fmaf(wx0, g01, wx1 * g11);
    float bil  = fmaf(wy0, rowA, wy1 * rowB);
    float neighbor = bil + 1.0f;

    float hd = t_c - neighbor;

    float v = v_io;
    float s = s_io;

    float hds  = ((hd - heps) > 0.0f) ? 1.0f : 0.0f;     // sign(relu(hd-eps))
    float nhd  = hds * fmaxf(hd, minhd);
    float q1 = nhd / CELLW;
    float q2 = q1 * v;
    float q3 = q2 * w;
    float sdiff = fmaf(-q3, sccr, s);                    // s - sed_cap
    float ftb   = (hd < 0.0f) ? 1.0f : 0.0f;             // relu(sign(-hd))
    float first = fminf(fmaxf(-hd, 0.0f), s);
    float ra = fmaxf(sdiff * depo, 0.0f);
    float rb = fmaxf((-sdiff) * diss, 0.0f);
    float deparg = fmaf(1.0f - ftb, ra - rb, first);
    float dep    = fmaxf(-fmaxf(hd, 0.0f), deparg);

    float s_new = s - dep;
    float t_new = t_c + dep;

    float rn = fmaxf(-fdy, 0.0f);
    float rm = fmaxf(1.0f - fabsf(fdy), 0.0f);
    float rp = fmaxf(fdy, 0.0f);

    float s1 = (c == WW - 1) ? 0.0f : rn * s_new;
    float s3 = (c == 0)      ? 0.0f : rp * s_new;
    s_io = fmaf(rm, s_new, s1) + s3;

    float w1 = (c == WW - 1) ? 0.0f : rn * w;
    float w3 = (c == 0)      ? 0.0f : rp * w;
    float wd = fmaf(rm, w, w1) + w3;
    w_io = wd * (1.0f - evapr);

    v_io = (gravr * hd) / CELLW;

    if (fin) {
        float aa = fmaf(-t_new, 2.0f, 1.0f);             // 1 - t*2 -> fnma
        float bq = 1.0f + aa;
        t_out = fmaxf(bq, 0.0f) - 1.0f;
    } else {
        t_out = t_new;
    }
}

// ---------------------------------------------------------------- coop path
struct Args {
    const float* in_terr;
    float*       T0;      // d_out: even-step source, final output
    float*       T1;      // ws
    const float* rain;    // (10, W, W)
    const float* gno;     // (10, W, W)
    const float* p_rr; const float* p_evap; const float* p_minhd;
    const float* p_heps; const float* p_grav; const float* p_scc;
    const float* p_diss; const float* p_depo;
};

__global__ __launch_bounds__(MTHR, 4) void erosion_mega(Args a)
{
    #pragma clang fp contract(off)
    cg::grid_group grid = cg::this_grid();

    const int base = blockIdx.x * (MTHR * CELLS) + threadIdx.x;

    float rr    = fmaxf(a.p_rr[0], 0.0f);
    float evapr = fmaxf(a.p_evap[0], 0.0f);
    float minhd = a.p_minhd[0];
    float heps  = a.p_heps[0];
    float gravr = fmaxf(a.p_grav[0], 0.0f);
    float sccr  = fmaxf(a.p_scc[0], 0.0f);
    float diss  = a.p_diss[0];
    float depo  = a.p_depo[0];

    float sA[CELLS], wA[CELLS], vA[CELLS];
    #pragma unroll
    for (int k = 0; k < CELLS; ++k) {
        int idx = base + k * MTHR;
        a.T0[idx] = (1.0f - a.in_terr[idx]) / 2.0f;
        sA[k] = 0.0f; wA[k] = 0.0f; vA[k] = 0.0f;
    }
    grid.sync();   // includes grid-wide release/acquire ordering

    #pragma unroll 1
    for (int it = 0; it < 10; ++it) {
        const float* tin  = (it & 1) ? a.T1 : a.T0;
        float*       tout = (it & 1) ? a.T0 : a.T1;
        const float* rain = a.rain + it * NPIX;
        const float* gno  = a.gno  + it * NPIX;
        const bool   fin  = (it == 9);

        #pragma unroll
        for (int k = 0; k < CELLS; ++k) {
            int idx = base + k * MTHR;
            int rem = idx & (NPIX - 1);
            int r   = rem >> 9;
            int c   = rem & (WW - 1);
            const float* tb = tin + (idx - rem);
            float t_res;
            cell_step(tb, rem, r, c, tb[rem], rain[rem], gno[rem],
                      rr, evapr, minhd, heps, gravr, sccr, diss, depo,
                      sA[k], wA[k], vA[k], t_res, fin);
            tout[idx] = t_res;
        }

        if (it != 9) grid.sync();
    }
}

// ---------------------------------------------------------------- fallback (r6)
__global__ __launch_bounds__(256) void erosion_init(
    const float* __restrict__ in, float* __restrict__ terr,
    float* __restrict__ sed, float* __restrict__ wat, float* __restrict__ vel)
{
    #pragma clang fp contract(off)
    int idx = blockIdx.x * 256 + threadIdx.x;
    terr[idx] = (1.0f - in[idx]) / 2.0f;
    sed[idx] = 0.0f;
    wat[idx] = 0.0f;
    vel[idx] = 0.0f;
}

__global__ __launch_bounds__(256) void erosion_step(
    const float* __restrict__ terr_in, float* __restrict__ terr_out,
    float* __restrict__ sed, float* __restrict__ wat, float* __restrict__ vel,
    const float* __restrict__ rain, const float* __restrict__ gnoise,
    const float* __restrict__ s_rain_rate, const float* __restrict__ s_evap,
    const float* __restrict__ s_minhd, const float* __restrict__ s_heps,
    const float* __restrict__ s_grav, const float* __restrict__ s_scc,
    const float* __restrict__ s_diss, const float* __restrict__ s_depo,
    int final_flag)
{
    #pragma clang fp contract(off)
    int idx = blockIdx.x * 256 + threadIdx.x;
    int rem = idx & (NPIX - 1);
    int r   = rem >> 9;
    int c   = rem & (WW - 1);
    const float* tb = terr_in + (long)(idx - rem);

    float rr    = fmaxf(s_rain_rate[0], 0.0f);
    float evapr = fmaxf(s_evap[0], 0.0f);
    float minhd = s_minhd[0];
    float heps  = s_heps[0];
    float gravr = fmaxf(s_grav[0], 0.0f);
    float sccr  = fmaxf(s_scc[0], 0.0f);
    float diss  = s_diss[0];
    float depo  = s_depo[0];

    float s = sed[idx], w0 = wat[idx], v = vel[idx];
    float t_res;
    cell_step(tb, rem, r, c, tb[rem], rain[rem], gnoise[rem],
              rr, evapr, minhd, heps, gravr, sccr, diss, depo,
              s, w0, v, t_res, final_flag != 0);
    sed[idx] = s; wat[idx] = w0; vel[idx] = v;
    terr_out[idx] = t_res;
}

// ---------------------------------------------------------------- launch
extern "C" void kernel_launch(void* const* d_in, const int* in_sizes, int n_in,
                              void* d_out, int out_size, void* d_ws, size_t ws_size,
                              hipStream_t stream) {
    Args a;
    a.in_terr = (const float*)d_in[0];
    a.rain    = (const float*)d_in[1];
    a.gno     = (const float*)d_in[2];
    a.p_rr    = (const float*)d_in[3];
    a.p_evap  = (const float*)d_in[4];
    a.p_minhd = (const float*)d_in[5];
    a.p_heps  = (const float*)d_in[6];
    a.p_grav  = (const float*)d_in[7];
    a.p_scc   = (const float*)d_in[8];
    a.p_diss  = (const float*)d_in[9];
    a.p_depo  = (const float*)d_in[10];
    a.T0      = (float*)d_out;
    a.T1      = (float*)d_ws;

    // Host-side routing (capture-legal, deterministic).
    bool coop_ok = false;
    int dev = 0;
    (void)hipGetDevice(&dev);
    int numCU = 0;
    if (hipDeviceGetAttribute(&numCU, hipDeviceAttributeMultiprocessorCount, dev) == hipSuccess) {
        int perCU = 0;
        if (hipOccupancyMaxActiveBlocksPerMultiprocessor(&perCU, (const void*)erosion_mega,
                                                         MTHR, 0) == hipSuccess) {
            coop_ok = ((long)perCU * numCU >= NBLK);
        }
    }

    if (coop_ok) {
        void* kargs[] = { &a };
        if (hipLaunchCooperativeKernel((void*)erosion_mega, dim3(NBLK), dim3(MTHR),
                                       kargs, 0, stream) == hipSuccess)
            return;
    }

    // Fallback: proven r6 multi-kernel sequence (442 us, absmax 0.0273).
    float* T0  = (float*)d_out;
    float* ws  = (float*)d_ws;
    float* T1  = ws;
    float* sed = ws + (size_t)NTOT;
    float* wat = ws + (size_t)2 * NTOT;
    float* vel = ws + (size_t)3 * NTOT;

    dim3 grid(NTOT / 256), block(256);
    erosion_init<<<grid, block, 0, stream>>>(a.in_terr, T0, sed, wat, vel);
    for (int it = 0; it < 10; ++it) {
        const float* tin  = (it & 1) ? T1 : T0;
        float*       tout = (it & 1) ? T0 : T1;
        erosion_step<<<grid, block, 0, stream>>>(
            tin, tout, sed, wat, vel,
            a.rain + (size_t)it * NPIX, a.gno + (size_t)it * NPIX,
            a.p_rr, a.p_evap, a.p_minhd, a.p_heps, a.p_grav, a.p_scc,
            a.p_diss, a.p_depo, (it == 9) ? 1 : 0);
    }
}